// Round 14
// baseline (24.219 us; speedup 1.0000x reference)
//
#include <hip/hip_runtime.h>

// Chamfer loss via 32x32x16 MFMA, max-occupancy variant. X,Y f32 [8,3,4096].
// dir 0: queries = X, targets = Y; dir 1: queries = Y, targets = X.
//
// d'(q,t) = ||t||^2 - 2 q.t with hi/lo-split bf16 (verified R6-R13):
//   k0..11: per coord: Q=(qh,qh,ql,ql) (qh+ql ~= -2q_c), T=(th,tl,th,tl)
//   k12,13: Q=(1,1), T=(rt_hi,rt_lo); k14,15 = 0.  K=16 exact.
// Swapped operands (R12): D = mfma(A=targets, B=queries) -> col = query =
// lane-local; 16 regs = 16 targets; epilogue = VALU tree + 1 shfl_xor(32).
//
// R14 vs R13: TLP instead of ILP. <=64-VGPR core (1 strip/wave, 1 tile/step,
// NO prefetch, live ~50 regs) + __launch_bounds__(256,8) -> 8 waves/SIMD,
// 8 co-resident blocks/CU (16 KB LDS each). ds_read/MFMA latency hidden by
// wave interleave, not scheduling slack. Grid 4096 = 16 pairs x 32 qgroups
// x 8 slices (512 targets each), 2 scheduling rounds/CU.
// reduce: 64 blocks min over 8 slices + sum; poison-proof handshake.

typedef __attribute__((ext_vector_type(8))) short short8;
typedef __attribute__((ext_vector_type(16))) float f32x16;
typedef __attribute__((ext_vector_type(4))) unsigned uint4v;

constexpr int NPTS  = 4096;
constexpr int NB    = 8;
constexpr int NQ    = 2 * NB * NPTS;      // 65536 query slots
constexpr int TSN   = 8;                  // target slices
constexpr int TGT   = 512;                // targets per slice
constexpr int TILES = TGT / 32;           // 16
constexpr int GRID_MAIN  = 16 * 32 * TSN; // 4096
constexpr int RED_BLOCKS = 64;

__device__ inline unsigned short f2bf(float x) {      // round-to-nearest-even
    unsigned u = __float_as_uint(x);
    unsigned r = u + 0x7fff + ((u >> 16) & 1);
    return (unsigned short)(r >> 16);
}
__device__ inline float bf2f(unsigned short h) {
    return __uint_as_float(((unsigned)h) << 16);
}
__device__ inline unsigned pack2(unsigned short a, unsigned short b) {
    return (unsigned)a | ((unsigned)b << 16);
}

__global__ __launch_bounds__(256, 8) void chamfer_main(
    const float* __restrict__ X, const float* __restrict__ Y,
    float* __restrict__ minq)
{
    __shared__ char BL[TGT * 32];         // 16 KB

    const int bid  = blockIdx.x;
    const int ts   = bid & 7;
    const int qg   = (bid >> 3) & 31;
    const int pair = bid >> 8;            // dir*8 + b
    const int dir  = pair >> 3, b = pair & 7;
    const int tid  = threadIdx.x;
    const int lane = tid & 63, wv = tid >> 6;
    const int c    = lane & 31, h = lane >> 5;

    const float* __restrict__ Qraw = (dir ? Y : X) + b * 3 * NPTS;
    const float* __restrict__ Traw = (dir ? X : Y) + b * 3 * NPTS;

    // ---- pack this block's 512-target slice into LDS (32 B per point) ----
    // half-swap swizzle (R10/R13-verified): halves at p*32 + ((hf^((p>>2)&1))<<4).
    #pragma unroll
    for (int k = 0; k < 2; ++k) {
        const int p = k * 256 + tid;                     // 0..511
        const int i = ts * TGT + p;
        float tx = Traw[i], ty = Traw[NPTS + i], tz = Traw[2 * NPTS + i];
        float r  = fmaf(tx, tx, fmaf(ty, ty, tz * tz));
        unsigned short hx = f2bf(tx), lx = f2bf(tx - bf2f(hx));
        unsigned short hy = f2bf(ty), ly = f2bf(ty - bf2f(hy));
        unsigned short hz = f2bf(tz), lz = f2bf(tz - bf2f(hz));
        unsigned short hr = f2bf(r),  lr = f2bf(r  - bf2f(hr));
        unsigned w0 = pack2(hx, lx), w2 = pack2(hy, ly), w4 = pack2(hz, lz);
        unsigned w6 = pack2(hr, lr);
        uint4v lo = {w0, w0, w2, w2};                    // k0..7
        uint4v hi = {w4, w4, w6, 0u};                    // k8..15
        const int sw = (p >> 2) & 1;
        *(uint4v*)(BL + p * 32 + ((0 ^ sw) << 4)) = lo;
        *(uint4v*)(BL + p * 32 + ((1 ^ sw) << 4)) = hi;
    }

    // ---- B fragment (queries): ONE strip of 32 per wave ----
    // B lane map (32x32x16): col = lane&31, k = h*8 + j.
    union Frag { uint4v u; short8 s; };
    Frag qfr;
    float ra;
    {
        const int q = qg * 128 + wv * 32 + c;
        float qx = Qraw[q], qy = Qraw[NPTS + q], qz = Qraw[2 * NPTS + q];
        ra = fmaf(qx, qx, fmaf(qy, qy, qz * qz));
        float mx = -2.f * qx, my = -2.f * qy, mz = -2.f * qz;
        unsigned short hx = f2bf(mx), lx = f2bf(mx - bf2f(hx));
        unsigned short hy = f2bf(my), ly = f2bf(my - bf2f(hy));
        unsigned short hz = f2bf(mz), lz = f2bf(mz - bf2f(hz));
        uint4v f0 = {pack2(hx, hx), pack2(lx, lx), pack2(hy, hy), pack2(ly, ly)};
        uint4v f1 = {pack2(hz, hz), pack2(lz, lz), 0x3F803F80u, 0u};
        qfr.u = h ? f1 : f0;
    }

    __syncthreads();                                     // targets staged

    // ---- main loop: 16 tiles of 32 targets, 1 tile/step, no prefetch ----
    // (latency hidden by 8 waves/SIMD round-robin, not by ILP)
    f32x16 run;
    #pragma unroll
    for (int i = 0; i < 16; ++i) run[i] = 3.4e38f;
    f32x16 zacc;
    #pragma unroll
    for (int i = 0; i < 16; ++i) zacc[i] = 0.f;

    // A lane map (targets): row = lane&31 (target in tile), k = h*8+j -> 16 B.
    const char* base = BL + c * 32 + ((h ^ ((c >> 2) & 1)) << 4);

    for (int t = 0; t < TILES; ++t) {
        short8 tf = *(const short8*)(base + t * 1024);   // ds_read_b128
        f32x16 dA = __builtin_amdgcn_mfma_f32_32x32x16_bf16(tf, qfr.s, zacc, 0, 0, 0);
        #pragma unroll
        for (int i = 0; i < 16; ++i)
            run[i] = fminf(run[i], dA[i]);
    }

    // ---- epilogue: min over 16 target-regs (VALU tree) + one h-half swap ----
    {
        float m0 = fminf(fminf(run[0],  run[1]),  fminf(run[2],  run[3]));
        float m1 = fminf(fminf(run[4],  run[5]),  fminf(run[6],  run[7]));
        float m2 = fminf(fminf(run[8],  run[9]),  fminf(run[10], run[11]));
        float m3 = fminf(fminf(run[12], run[13]), fminf(run[14], run[15]));
        float m  = fminf(fminf(m0, m1), fminf(m2, m3));
        m = fminf(m, __shfl_xor(m, 32));                 // combine h halves
        m += ra;                                         // ra + slice-min
        if (h == 0)
            minq[(size_t)ts * NQ + pair * 4096 + qg * 128 + wv * 32 + c] = m;
    }
}

__global__ __launch_bounds__(256) void chamfer_reduce(
    const float4* __restrict__ mq4, float* __restrict__ partials,
    unsigned* __restrict__ counter, float* __restrict__ out)
{
    __shared__ float wsum[4];
    __shared__ int   fireFlag;
    const int tid = threadIdx.x;
    const int lane = tid & 63, wv = tid >> 6;
    const int idx = blockIdx.x * 256 + tid;              // 0..16383 float4 slots

    float4 m = mq4[idx];
    #pragma unroll
    for (int s = 1; s < TSN; ++s) {
        float4 v = mq4[(size_t)s * (NQ / 4) + idx];
        m.x = fminf(m.x, v.x); m.y = fminf(m.y, v.y);
        m.z = fminf(m.z, v.z); m.w = fminf(m.w, v.w);
    }
    float v = (m.x + m.y) + (m.z + m.w);
    #pragma unroll
    for (int off = 1; off < 64; off <<= 1) v += __shfl_xor(v, off);
    if (lane == 0) wsum[wv] = v;
    __syncthreads();
    if (tid == 0) {
        partials[blockIdx.x] = (wsum[0] + wsum[1]) + (wsum[2] + wsum[3]);
        __threadfence();                                 // publish partial
        unsigned old = atomicAdd(counter, 1u);           // device-scope
        fireFlag = ((old & 63u) == 63u);                 // poison-proof
    }
    __syncthreads();

    if (fireFlag) {
        __threadfence();                                 // acquire partials
        if (tid < 64) {
            float p = partials[tid];                     // exactly 64 partials
            #pragma unroll
            for (int off = 1; off < 64; off <<= 1) p += __shfl_xor(p, off);
            if (tid == 0)
                out[0] = p * (1.0f / 65536.0f);          // mean of (d1+d2)/2
        }
    }
}

extern "C" void kernel_launch(void* const* d_in, const int* in_sizes, int n_in,
                              void* d_out, int out_size, void* d_ws, size_t ws_size,
                              hipStream_t stream) {
    const float* X = (const float*)d_in[0];
    const float* Y = (const float*)d_in[1];

    float*    minq     = (float*)d_ws;                         // 8*65536 f32 = 2 MB
    float*    partials = minq + (size_t)TSN * NQ;              // 64 f32
    unsigned* counter  = (unsigned*)(partials + RED_BLOCKS);   // 1 u32 (any init OK)
    float*    out      = (float*)d_out;

    chamfer_main<<<GRID_MAIN, 256, 0, stream>>>(X, Y, minq);
    chamfer_reduce<<<RED_BLOCKS, 256, 0, stream>>>(
        (const float4*)minq, partials, counter, out);
}